// Round 6
// baseline (397.446 us; speedup 1.0000x reference)
//
#include <hip/hip_runtime.h>
#include <hip/hip_bf16.h>

typedef unsigned short u16;
typedef unsigned char u8;
typedef __attribute__((ext_vector_type(8))) short bf16x8;
typedef __attribute__((ext_vector_type(4))) float f32x4;

#define MFMA_BF16(a,b,c) __builtin_amdgcn_mfma_f32_16x16x32_bf16((a),(b),(c),0,0,0)
#define LOG2E 1.4426950408889634f
#define SQSCALE 0.18033688011112042f   // 0.125 * LOG2E

__device__ __forceinline__ u16 f2b(float f) {
    __hip_bfloat16 h = __float2bfloat16(f);
    u16 u; __builtin_memcpy(&u, &h, 2); return u;
}
// RNE f32->bf16 for known-finite non-NaN values
__device__ __forceinline__ unsigned f2b_fast(float f) {
    unsigned u; __builtin_memcpy(&u, &f, 4);
    return (u + 0x7FFFu + ((u >> 16) & 1u)) >> 16;
}
__device__ __forceinline__ f32x4 zero4() { f32x4 z = {0.f,0.f,0.f,0.f}; return z; }

// ---------------- convert x (f32) -> bf16, 8 elems/thread ----------------
__global__ __launch_bounds__(256) void convX(const float* __restrict__ in, u16* __restrict__ out) {
    size_t i = ((size_t)blockIdx.x * 256 + threadIdx.x) * 8;
    float4 a = *(const float4*)(in + i);
    float4 b = *(const float4*)(in + i + 4);
    union { u16 s[8]; uint4 v; } u;
    u.s[0]=f2b(a.x); u.s[1]=f2b(a.y); u.s[2]=f2b(a.z); u.s[3]=f2b(a.w);
    u.s[4]=f2b(b.x); u.s[5]=f2b(b.y); u.s[6]=f2b(b.z); u.s[7]=f2b(b.w);
    *(uint4*)(out + i) = u.v;
}

// ------ weight transpose+convert: in [768][C] f32 -> out [C][768] bf16 ------
__global__ __launch_bounds__(256) void convTW(const float* __restrict__ in, u16* __restrict__ out, int C) {
    __shared__ __align__(16) u16 T[64][68];
    int c0 = blockIdx.x * 64, k0 = blockIdx.y * 64;
    int tid = threadIdx.x;
#pragma unroll
    for (int i = 0; i < 4; ++i) {
        int id = tid + i * 256;
        int row = id >> 4, ch = id & 15;
        float4 v = *(const float4*)(in + (size_t)(k0 + row) * C + c0 + ch * 4);
        T[row][ch*4+0] = f2b(v.x); T[row][ch*4+1] = f2b(v.y);
        T[row][ch*4+2] = f2b(v.z); T[row][ch*4+3] = f2b(v.w);
    }
    __syncthreads();
#pragma unroll
    for (int i = 0; i < 2; ++i) {
        int id = tid + i * 256;
        int c = id >> 3, ch = id & 7;
        union { u16 s[8]; uint4 v; } u;
#pragma unroll
        for (int j = 0; j < 8; ++j) u.s[j] = T[ch*8+j][c];
        *(uint4*)(out + (size_t)(c0 + c) * 768 + k0 + ch * 8) = u.v;
    }
}

// ------ V transpose: qkv [4096][2304] (V slice) -> Vt [bh][64][2048] bf16 ------
__global__ __launch_bounds__(256) void transV(const u16* __restrict__ qkv, u16* __restrict__ Vt) {
    __shared__ __align__(16) u16 T[64][72];
    int blk = blockIdx.x;
    int n0 = (blk & 31) * 64, bh = blk >> 5;
    int b = bh / 12, h = bh - b * 12;
    int tid = threadIdx.x;
    int row = tid >> 2, sc = (tid & 3) * 2;
    const uint4* s = (const uint4*)(qkv + (size_t)(b*2048 + n0 + row) * 2304 + 1536 + h*64);
    *(uint4*)&T[row][sc*8]   = s[sc];
    *(uint4*)&T[row][sc*8+8] = s[sc+1];
    __syncthreads();
#pragma unroll
    for (int i = 0; i < 2; ++i) {
        int id = tid + i * 256;
        int hd = id >> 3, ch = id & 7;
        union { u16 s2[8]; uint4 v; } u;
#pragma unroll
        for (int j = 0; j < 8; ++j) u.s2[j] = T[ch*8+j][hd];
        *(uint4*)(Vt + ((size_t)bh * 64 + hd) * 2048 + n0 + ch * 8) = u.v;
    }
}

// ------ dist+mask fuse: dist8[b][i][j] = mask[b][j] ? 32 : clip(dist,0,31), u8 ------
// mask encoding auto-detected (int32/byte/f32/bf16) from first 4KB (safe in all encodings).
__global__ __launch_bounds__(256)
void distU8(const int* __restrict__ dist, const unsigned* __restrict__ m, u8* __restrict__ out) {
    __shared__ int sB, sH, sF;
    if (threadIdx.x == 0) { sB = 0; sH = 0; sF = 0; }
    __syncthreads();
    int lb = 0, lh = 0, lf = 0;
#pragma unroll
    for (int i = 0; i < 4; ++i) {
        unsigned v = m[threadIdx.x + i * 256];
        if (v == 0x3f800000u) { lf = 1; }
        else if (v > 1u) {
            unsigned b0 = v & 0xffu, b1 = (v >> 8) & 0xffu, b2 = (v >> 16) & 0xffu, b3 = v >> 24;
            bool bytesOK = (b0 <= 1u) && (b1 <= 1u) && (b2 <= 1u) && (b3 <= 1u);
            unsigned h0 = v & 0xffffu, h1 = v >> 16;
            bool halfOK = (h0 == 0u || h0 == 0x3f80u) && (h1 == 0u || h1 == 0x3f80u);
            if (bytesOK) lb = 1; else if (halfOK) lh = 1;
        }
    }
    if (lb) atomicOr(&sB, 1);
    if (lh) atomicOr(&sH, 1);
    if (lf) atomicOr(&sF, 1);
    __syncthreads();
    const int mode = sH ? 3 : (sB ? 1 : (sF ? 2 : 0));
    const u8* m8 = (const u8*)m;
    const u16* mh = (const u16*)m;
    const float* mf = (const float*)m;
    const int* mi = (const int*)m;

    size_t e0 = ((size_t)blockIdx.x * 256 + threadIdx.x) * 16;   // 16 consecutive elems, one row
    size_t row = e0 >> 11;            // global (b*2048+i)
    int b = (int)(row >> 11);
    int j = (int)(e0 & 2047);
    int mbase = b * 2048 + j;
    union { u8 s[16]; uint4 v; } o;
#pragma unroll
    for (int k = 0; k < 16; ++k) {
        int d = dist[e0 + k];
        d = d < 0 ? 0 : (d > 31 ? 31 : d);
        int mv;
        if (mode == 0)      mv = (mi[mbase + k] != 0);
        else if (mode == 1) mv = (m8[mbase + k] != 0);
        else if (mode == 2) mv = (mf[mbase + k] != 0.0f);
        else                mv = (mh[mbase + k] != 0);
        o.s[k] = mv ? 32 : (u8)d;
    }
    *(uint4*)(out + e0) = o.v;
}

// ------ GEMM QKV: C = A[4096,768] * Bt[2304,768]^T + bias -> bf16 [4096][2304], Q cols scaled ------
__global__ __launch_bounds__(256)
void gemmQKV(const u16* __restrict__ A, const u16* __restrict__ Bt,
             const float* __restrict__ bias, u16* __restrict__ bO) {
    __shared__ __align__(16) u16 As[128][40];
    __shared__ __align__(16) u16 Bs[128][40];
    const int K = 768;
    const int tid = threadIdx.x;
    const int lane = tid & 63, w = tid >> 6;
    const int wm = w >> 1, wn = w & 1;
    const int l15 = lane & 15, q = lane >> 4;
    const int m0 = blockIdx.y * 128, n0 = blockIdx.x * 128;
    const int rowS = tid >> 1, cS = (tid & 1) * 2;
    const u16* Ag = A + (size_t)(m0 + rowS) * K;
    const u16* Bg = Bt + (size_t)(n0 + rowS) * K;
    uint4 pa0, pa1, pb0, pb1;
    { const uint4* sa = (const uint4*)Ag; pa0 = sa[cS]; pa1 = sa[cS+1];
      const uint4* sb = (const uint4*)Bg; pb0 = sb[cS]; pb1 = sb[cS+1]; }
    f32x4 acc[4][4];
#pragma unroll
    for (int i=0;i<4;++i)
#pragma unroll
        for (int j=0;j<4;++j) acc[i][j] = zero4();

    for (int kt = 0; kt < 24; ++kt) {
        __syncthreads();
        *(uint4*)&As[rowS][cS*8]   = pa0; *(uint4*)&As[rowS][cS*8+8] = pa1;
        *(uint4*)&Bs[rowS][cS*8]   = pb0; *(uint4*)&Bs[rowS][cS*8+8] = pb1;
        __syncthreads();
        if (kt < 23) {
            const uint4* sa = (const uint4*)(Ag + (kt+1)*32);
            pa0 = sa[cS]; pa1 = sa[cS+1];
            const uint4* sb = (const uint4*)(Bg + (kt+1)*32);
            pb0 = sb[cS]; pb1 = sb[cS+1];
        }
        bf16x8 af[4], bfr[4];
#pragma unroll
        for (int mt=0; mt<4; ++mt) af[mt]  = *(const bf16x8*)&As[wm*64+mt*16+l15][q*8];
#pragma unroll
        for (int nt=0; nt<4; ++nt) bfr[nt] = *(const bf16x8*)&Bs[wn*64+nt*16+l15][q*8];
#pragma unroll
        for (int mt=0; mt<4; ++mt)
#pragma unroll
            for (int nt=0; nt<4; ++nt)
                acc[mt][nt] = MFMA_BF16(af[mt], bfr[nt], acc[mt][nt]);
    }
#pragma unroll
    for (int mt=0; mt<4; ++mt) {
#pragma unroll
        for (int nt=0; nt<4; ++nt) {
            int n = n0 + wn*64 + nt*16 + l15;
            float bv = bias[n];
            float scl = (n < 768) ? SQSCALE : 1.0f;
#pragma unroll
            for (int r=0; r<4; ++r) {
                int mm = m0 + wm*64 + mt*16 + q*4 + r;
                bO[(size_t)mm*2304 + n] = f2b((acc[mt][nt][r] + bv) * scl);
            }
        }
    }
}

// ------ GEMM out: C = A[4096,768]bf16 * Bt[768,768]^T + bias -> f32. 64x64 tiles ------
__global__ __launch_bounds__(256)
void gemmOut(const u16* __restrict__ A, const u16* __restrict__ Bt,
             const float* __restrict__ bias, float* __restrict__ fO) {
    __shared__ __align__(16) u16 As[64][40];
    __shared__ __align__(16) u16 Bs[64][40];
    const int K = 768;
    const int tid = threadIdx.x;
    const int lane = tid & 63, w = tid >> 6;
    const int wm = w >> 1, wn = w & 1;
    const int l15 = lane & 15, q = lane >> 4;
    const int m0 = blockIdx.y * 64, n0 = blockIdx.x * 64;
    const int rowS = tid >> 2, cS = tid & 3;
    const u16* Ag = A + (size_t)(m0 + rowS) * K;
    const u16* Bg = Bt + (size_t)(n0 + rowS) * K;
    uint4 pa, pb;
    { pa = ((const uint4*)Ag)[cS]; pb = ((const uint4*)Bg)[cS]; }
    f32x4 acc[2][2];
#pragma unroll
    for (int i=0;i<2;++i)
#pragma unroll
        for (int j=0;j<2;++j) acc[i][j] = zero4();

    for (int kt = 0; kt < 24; ++kt) {
        __syncthreads();
        *(uint4*)&As[rowS][cS*8] = pa;
        *(uint4*)&Bs[rowS][cS*8] = pb;
        __syncthreads();
        if (kt < 23) {
            pa = ((const uint4*)(Ag + (kt+1)*32))[cS];
            pb = ((const uint4*)(Bg + (kt+1)*32))[cS];
        }
        bf16x8 af[2], bfr[2];
#pragma unroll
        for (int mt=0; mt<2; ++mt) af[mt]  = *(const bf16x8*)&As[wm*32+mt*16+l15][q*8];
#pragma unroll
        for (int nt=0; nt<2; ++nt) bfr[nt] = *(const bf16x8*)&Bs[wn*32+nt*16+l15][q*8];
#pragma unroll
        for (int mt=0; mt<2; ++mt)
#pragma unroll
            for (int nt=0; nt<2; ++nt)
                acc[mt][nt] = MFMA_BF16(af[mt], bfr[nt], acc[mt][nt]);
    }
#pragma unroll
    for (int mt=0; mt<2; ++mt) {
#pragma unroll
        for (int nt=0; nt<2; ++nt) {
            int n = n0 + wn*32 + nt*16 + l15;
            float bv = bias[n];
#pragma unroll
            for (int r=0; r<4; ++r) {
                int mm = m0 + wm*32 + mt*16 + q*4 + r;
                fO[(size_t)mm*768 + n] = acc[mt][nt][r] + bv;
            }
        }
    }
}

// ------ flash attention, S^T formulation, XCD-affinity swizzle, fused dist8 bias+mask ------
__global__ __launch_bounds__(256)
void flashAttn(const u16* __restrict__ qkv, const u16* __restrict__ Vt,
               const u8* __restrict__ dist8, const float* __restrict__ btg,
               u16* __restrict__ attnout) {
    __shared__ float bt[33];
    __shared__ __align__(16) u16 Os[4][16][72];
    const int tid = threadIdx.x;
    const int lane = tid & 63, w = tid >> 6;
    const int l15 = lane & 15, q = lane >> 4;
    // XCD-affinity decode: xcd = n&7 holds bh in {xcd, xcd+8, xcd+16}; same-it blocks adjacent.
    const int n = blockIdx.x;
    const int xcd = n & 7, k = n >> 3;
    const int g = k % 3, it = k / 3;
    const int bh = xcd + 8 * g;
    const int b = bh / 12, h = bh - 12 * b;
    const int i0 = it * 64;
    const float NEG_INF = -__builtin_inff();
    if (tid < 33) bt[tid] = (tid < 32) ? btg[tid*12 + h] * LOG2E : NEG_INF;  // [32] = masked
    __syncthreads();

    const int iRow = i0 + w*16 + l15;
    const u16* Qp = qkv + ((size_t)(b*2048 + iRow))*2304 + h*64;
    bf16x8 qB0 = *(const bf16x8*)(Qp + q*8);
    bf16x8 qB1 = *(const bf16x8*)(Qp + 32 + q*8);
    const u16* Kbase = qkv + ((size_t)(b*2048 + l15))*2304 + 768 + h*64 + q*8;  // + j*2304
    const u16* Vr0 = Vt + ((size_t)bh*64 + l15)*2048 + q*8;                     // + j
    const u16* Vr1 = Vr0 + 16*2048;
    const u16* Vr2 = Vr0 + 32*2048;
    const u16* Vr3 = Vr0 + 48*2048;
    const u8* dpb = dist8 + ((size_t)(b*2048 + iRow))*2048 + q*4;               // + j0 + mt*16
    const int srcL0 = ((2*q)   & 3)*16 + l15;
    const int srcL1 = ((2*q+1) & 3)*16 + l15;

    f32x4 o0 = zero4(), o1 = zero4(), o2 = zero4(), o3 = zero4();
    float mI = NEG_INF, lI = 0.f;

    for (int jt = 0; jt < 32; ++jt) {
        const int j0 = jt * 64;
        const u16* kb = Kbase + (size_t)j0*2304;
        bf16x8 kA[4][2];
#pragma unroll
        for (int mt = 0; mt < 4; ++mt) {
            kA[mt][0] = *(const bf16x8*)(kb + (size_t)mt*16*2304);
            kA[mt][1] = *(const bf16x8*)(kb + (size_t)mt*16*2304 + 32);
        }
        unsigned dw[4];
#pragma unroll
        for (int mt = 0; mt < 4; ++mt) dw[mt] = *(const unsigned*)(dpb + j0 + mt*16);

        // --- S^T = K·Q^T ---
        f32x4 s0 = zero4(), s1 = zero4(), s2 = zero4(), s3 = zero4();
        s0 = MFMA_BF16(kA[0][0], qB0, s0); s0 = MFMA_BF16(kA[0][1], qB1, s0);
        s1 = MFMA_BF16(kA[1][0], qB0, s1); s1 = MFMA_BF16(kA[1][1], qB1, s1);
        s2 = MFMA_BF16(kA[2][0], qB0, s2); s2 = MFMA_BF16(kA[2][1], qB1, s2);
        s3 = MFMA_BF16(kA[3][0], qB0, s3); s3 = MFMA_BF16(kA[3][1], qB1, s3);

        bf16x8 vA[4][2];
        vA[0][0] = *(const bf16x8*)(Vr0 + j0); vA[0][1] = *(const bf16x8*)(Vr0 + j0 + 32);
        vA[1][0] = *(const bf16x8*)(Vr1 + j0); vA[1][1] = *(const bf16x8*)(Vr1 + j0 + 32);
        vA[2][0] = *(const bf16x8*)(Vr2 + j0); vA[2][1] = *(const bf16x8*)(Vr2 + j0 + 32);
        vA[3][0] = *(const bf16x8*)(Vr3 + j0); vA[3][1] = *(const bf16x8*)(Vr3 + j0 + 32);

        // --- bias+mask via fused table: sv = s + bt[byte] (byte==32 -> -inf) ---
        float sv[4][4];
#pragma unroll
        for (int mt = 0; mt < 4; ++mt) {
            const f32x4 sm = mt==0 ? s0 : (mt==1 ? s1 : (mt==2 ? s2 : s3));
#pragma unroll
            for (int r = 0; r < 4; ++r)
                sv[mt][r] = sm[r] + bt[(dw[mt] >> (8*r)) & 0xff];
        }

        // --- online softmax per column i ---
        float rm = sv[0][0];
#pragma unroll
        for (int mt = 0; mt < 4; ++mt)
#pragma unroll
            for (int r = 0; r < 4; ++r) rm = fmaxf(rm, sv[mt][r]);
        rm = fmaxf(rm, __shfl_xor(rm, 16, 64));
        rm = fmaxf(rm, __shfl_xor(rm, 32, 64));
        float mn = fmaxf(fmaxf(mI, rm), -1e30f);   // clamp: all-masked tile NaN-free
        float al = exp2f(mI - mn);
        float p[4][4]; float ps = 0.f;
#pragma unroll
        for (int mt = 0; mt < 4; ++mt)
#pragma unroll
            for (int r = 0; r < 4; ++r) { p[mt][r] = exp2f(sv[mt][r] - mn); ps += p[mt][r]; }
        ps += __shfl_xor(ps, 16, 64);
        ps += __shfl_xor(ps, 32, 64);
        lI = lI * al + ps;
        mI = mn;
#pragma unroll
        for (int r = 0; r < 4; ++r) { o0[r] *= al; o1[r] *= al; o2[r] *= al; o3[r] *= al; }

        // --- pack P, exchange C-layout -> B-frag layout, PV: O^T += V^T·P^T ---
        unsigned pk[4][2];
#pragma unroll
        for (int mt = 0; mt < 4; ++mt) {
            pk[mt][0] = f2b_fast(p[mt][0]) | (f2b_fast(p[mt][1]) << 16);
            pk[mt][1] = f2b_fast(p[mt][2]) | (f2b_fast(p[mt][3]) << 16);
        }
#pragma unroll
        for (int ks = 0; ks < 2; ++ks) {
            union { unsigned d[4]; bf16x8 v; } pb;
#pragma unroll
            for (int s = 0; s < 4; ++s) {
                int sl = (s >> 1) ? srcL1 : srcL0;
                int u0 = __shfl((int)pk[2*ks    ][s & 1], sl, 64);
                int u1 = __shfl((int)pk[2*ks + 1][s & 1], sl, 64);
                pb.d[s] = (q >> 1) ? (unsigned)u1 : (unsigned)u0;
            }
            o0 = MFMA_BF16(vA[0][ks], pb.v, o0);
            o1 = MFMA_BF16(vA[1][ks], pb.v, o1);
            o2 = MFMA_BF16(vA[2][ks], pb.v, o2);
            o3 = MFMA_BF16(vA[3][ks], pb.v, o3);
        }
    }

    // --- epilogue: normalize, LDS bounce O^T -> row-major, coalesced store ---
    float inv = 1.0f / lI;
#pragma unroll
    for (int r = 0; r < 4; ++r) {
        Os[w][l15][ 0 + q*4 + r] = f2b(o0[r] * inv);
        Os[w][l15][16 + q*4 + r] = f2b(o1[r] * inv);
        Os[w][l15][32 + q*4 + r] = f2b(o2[r] * inv);
        Os[w][l15][48 + q*4 + r] = f2b(o3[r] * inv);
    }
    __syncthreads();
    int rr = lane >> 2, cc = lane & 3;
    uint4 a0 = *(const uint4*)&Os[w][rr][cc*16];
    uint4 a1 = *(const uint4*)&Os[w][rr][cc*16 + 8];
    size_t orow = ((size_t)b*2048 + i0 + w*16 + rr)*768 + h*64 + cc*16;
    *(uint4*)(attnout + orow)     = a0;
    *(uint4*)(attnout + orow + 8) = a1;
}

extern "C" void kernel_launch(void* const* d_in, const int* in_sizes, int n_in,
                              void* d_out, int out_size, void* d_ws, size_t ws_size,
                              hipStream_t stream) {
    (void)in_sizes; (void)n_in; (void)out_size; (void)ws_size;
    const float* x      = (const float*)d_in[0];
    const int*   dist   = (const int*)d_in[1];
    const int*   mask   = (const int*)d_in[2];
    const float* qkv_w  = (const float*)d_in[3];
    const float* qkv_b  = (const float*)d_in[4];
    const float* out_w  = (const float*)d_in[5];
    const float* out_b  = (const float*)d_in[6];
    const float* btab   = (const float*)d_in[7];
    float* out = (float*)d_out;

    char* ws = (char*)d_ws;
    size_t off = 0;
    auto alloc = [&](size_t bytes) { void* p = ws + off; off += (bytes + 255) & ~(size_t)255; return p; };
    u16* xb      = (u16*)alloc((size_t)4096*768*2);
    u16* wqkvT   = (u16*)alloc((size_t)2304*768*2);
    u16* woutT   = (u16*)alloc((size_t)768*768*2);
    u16* qkvB    = (u16*)alloc((size_t)4096*2304*2);
    u16* Vtp     = (u16*)alloc((size_t)24*2048*64*2);
    u16* attnout = (u16*)alloc((size_t)4096*768*2);
    u8*  dist8   = (u8*)alloc((size_t)2*2048*2048);

    convX<<<1536, 256, 0, stream>>>(x, xb);
    convTW<<<dim3(36,12), 256, 0, stream>>>(qkv_w, wqkvT, 2304);
    convTW<<<dim3(12,12), 256, 0, stream>>>(out_w, woutT, 768);
    distU8<<<2048, 256, 0, stream>>>(dist, (const unsigned*)mask, dist8);
    gemmQKV<<<dim3(18,32), 256, 0, stream>>>(xb, wqkvT, qkv_b, qkvB);
    transV<<<768, 256, 0, stream>>>(qkvB, Vtp);
    flashAttn<<<768, 256, 0, stream>>>(qkvB, Vtp, dist8, btab, attnout);
    gemmOut<<<dim3(12,64), 256, 0, stream>>>(attnout, woutT, out_b, out);
}